// Round 9
// baseline (188.202 us; speedup 1.0000x reference)
//
#include <hip/hip_runtime.h>
#include <type_traits>

#define RES_ 0.16f
#define XMIN_ -51.2f
#define YMIN_ -51.2f
#define EPS_ 1e-5f
#define NEG_ -1000000000.0f

#define WPB 4  // waves per block

typedef _Float16 f16x8 __attribute__((ext_vector_type(8)));
typedef _Float16 f16x4 __attribute__((ext_vector_type(4)));
typedef _Float16 f16x2 __attribute__((ext_vector_type(2)));
typedef float f32x4 __attribute__((ext_vector_type(4)));

union F8u { f16x8 v; f16x2 h[4]; };
union F4u { f16x4 v; f16x2 h[2]; };

#if __has_builtin(__builtin_amdgcn_mfma_f32_16x16x16f16)
#define MFMA1_K16 1
#else
#define MFMA1_K16 0
#endif

// cvt_pkrtz returns __fp16x2 on this clang; launder to _Float16x2 (same bits)
static __device__ __forceinline__ f16x2 pkrtz(float a, float b) {
    return __builtin_bit_cast(f16x2, __builtin_amdgcn_cvt_pkrtz(a, b));
}

static __device__ __forceinline__ f16x2 relu2(f16x2 x) {
#if __has_builtin(__builtin_elementwise_max)
    const f16x2 z2 = (f16x2)(_Float16)0.f;
    return __builtin_elementwise_max(x, z2);   // v_pk_max_f16
#else
    f16x2 r;
    r[0] = x[0] > (_Float16)0.f ? x[0] : (_Float16)0.f;
    r[1] = x[1] > (_Float16)0.f ? x[1] : (_Float16)0.f;
    return r;
#endif
}

__global__ __launch_bounds__(256, 5) void pfn_kernel(
    const float* __restrict__ pillars,
    const int* __restrict__ coords,
    const int* __restrict__ npts_arr,
    const float* __restrict__ W1, const float* __restrict__ b1,
    const float* __restrict__ g1, const float* __restrict__ beta1,
    const float* __restrict__ m1, const float* __restrict__ v1,
    const float* __restrict__ W2, const float* __restrict__ b2,
    const float* __restrict__ g2, const float* __restrict__ beta2,
    const float* __restrict__ m2, const float* __restrict__ v2,
    float* __restrict__ out, int P)
{
    __shared__ float pts[WPB][32][4];                        // 2 KB
    __shared__ __align__(16) _Float16 h1s[WPB][32][72];      // 18 KB

    const int tid  = threadIdx.x;
    const int wave = tid >> 6;
    const int lane = tid & 63;
    const int quad = lane >> 4;
    const int col  = lane & 15;

    // ---- W1 (BN1-scale folded) as B-frags; z-correction row; bias ----
    // feat slots: {x,y,z,r,xo,yo,z,xo,yo,0..}  (z in slot 6; zo folded via acc init)
    float c1v[4], w16v[4];
#if MFMA1_K16
    f16x4 bw1[4];   // B[k=quad*4+j][n=nt*16+col], K padded 9->16
#else
    f16x8 bw1[4];   // B[k=quad*8+j][n=nt*16+col], K padded 9->32
#endif
#pragma unroll
    for (int nt = 0; nt < 4; ++nt) {
        const int n0 = nt * 16 + col;
        const float a1 = g1[n0] * rsqrtf(v1[n0] + EPS_);
        c1v[nt]  = fmaf(a1, b1[n0] - m1[n0], beta1[n0]);
        w16v[nt] = a1 * W1[6 * 64 + n0];
#if MFMA1_K16
#pragma unroll
        for (int j = 0; j < 4; ++j) {
            const int k = quad * 4 + j;
            bw1[nt][j] = (k < 9) ? (_Float16)(a1 * W1[k * 64 + n0]) : (_Float16)0.f;
        }
#else
#pragma unroll
        for (int j = 0; j < 8; ++j) {
            const int k = quad * 8 + j;
            bw1[nt][j] = (k < 9) ? (_Float16)(a1 * W1[k * 64 + n0]) : (_Float16)0.f;
        }
#endif
    }

    // ---- W2 (BN2-scale folded, k-rows permuted to match packed-h1 layout) ----
    // physical h1 index i holds original channel g(i) = (i&3)*16 + (i>>2)
    f16x8 bw2[2][4];
#pragma unroll
    for (int nt = 0; nt < 4; ++nt) {
        const int n0 = nt * 16 + col;
        const float a2 = g2[n0] * rsqrtf(v2[n0] + EPS_);
#pragma unroll
        for (int kt = 0; kt < 2; ++kt)
#pragma unroll
            for (int j = 0; j < 8; ++j) {
                const int phys = kt * 32 + quad * 8 + j;
                const int orig = (phys & 3) * 16 + (phys >> 2);
                bw2[kt][nt][j] = (_Float16)(a2 * W2[orig * 64 + n0]);
            }
    }
    // lane's own output-channel bias (applied AFTER the row-max; max is shift-equivariant)
    const float a2o   = g2[lane] * rsqrtf(v2[lane] + EPS_);
    const float c2own = fmaf(a2o, b2[lane] - m2[lane], beta2[lane]);

    const int nwaves = gridDim.x * WPB;
    int p = __builtin_amdgcn_readfirstlane(blockIdx.x * WPB + wave);
    if (p >= P) return;

    // ---- prefetch pillar 0 ----
    float2 pv = ((const float2*)(pillars + (size_t)p * 128))[lane];
    int np = npts_arr[p];
    int cy = coords[2 * p], cx = coords[2 * p + 1];

    while (true) {
        const int pn = p + nwaves;
        const bool has_next = pn < P;
        float2 pvn; int npn = 0, cyn = 0, cxn = 0;
        if (has_next) {                       // wave-uniform; issue loads early
            pvn = ((const float2*)(pillars + (size_t)pn * 128))[lane];
            npn = npts_arr[pn];
            cyn = coords[2 * pn]; cxn = coords[2 * pn + 1];
        }

        np = np < 0 ? 0 : (np > 32 ? 32 : np);
        const int npu = __builtin_amdgcn_readfirstlane(np);
        const float xc = ((float)cx + 0.5f) * RES_ + XMIN_;
        const float yc = ((float)cy + 0.5f) * RES_ + YMIN_;

        // ---- stage 32x4 points (float2/lane) ----
        ((float2*)&pts[wave][0][0])[lane] = pv;

        // ---- z-sum from registers: odd lanes hold z of point lane>>1 in pv.x ----
        float zv = ((lane & 1) && ((lane >> 1) < np)) ? pv.x : 0.0f;
#pragma unroll
        for (int off = 1; off <= 32; off <<= 1) zv += __shfl_xor(zv, off, 64);
        const float z_mean = zv / fmaxf((float)np, 1.0f);

        __threadfence_block();   // drain pts writes (wave-lockstep)

        // ================= pillar body, specialized on row-tile count =================
        auto body = [&](auto MTC) -> float {
            constexpr int MT = decltype(MTC)::value;

            // ---- layer-1 A-frags ----
#if MFMA1_K16
            f16x4 av1[MT];   // A[m=mt*16+col][k=quad*4+j]
#else
            f16x8 av1[MT];   // A[m=mt*16+col][k=quad*8+j]
#endif
#pragma unroll
            for (int mt = 0; mt < MT; ++mt) {
                const float4 pt = *(const float4*)&pts[wave][mt * 16 + col][0];
                const float xo = pt.x - xc;
                const float yo = pt.y - yc;
                const f16x2 c01 = pkrtz(pt.x, pt.y);
                const f16x2 c23 = pkrtz(pt.z, pt.w);
                const f16x2 c45 = pkrtz(xo, yo);
                const f16x2 c67 = pkrtz(pt.z, xo);   // slot6=z (zo corrected in C), slot7=xo
                const f16x2 c89 = pkrtz(yo, 0.0f);
                const f16x2 z2  = (f16x2)(_Float16)0.f;
#if MFMA1_K16
                F4u u;
                u.h[0] = (quad == 0) ? c01 : (quad == 1) ? c45 : (quad == 2) ? c89 : z2;
                u.h[1] = (quad == 0) ? c23 : (quad == 1) ? c67 : z2;
                av1[mt] = u.v;
#else
                F8u u;
                u.h[0] = (quad == 0) ? c01 : (quad == 1) ? c89 : z2;
                u.h[1] = (quad == 0) ? c23 : z2;
                u.h[2] = (quad == 0) ? c45 : z2;
                u.h[3] = (quad == 0) ? c67 : z2;
                av1[mt] = u.v;
#endif
            }

            // ---- layer-1 in nt-PAIRS (acc1 peak 16 regs, not 32) ----
#pragma unroll
            for (int pp = 0; pp < 2; ++pp) {
                f32x4 acc1[MT][2];
#pragma unroll
                for (int ntl = 0; ntl < 2; ++ntl) {
                    const int nt = pp * 2 + ntl;
                    const float ci = fmaf(-z_mean, w16v[nt], c1v[nt]);
                    const f32x4 cinit = {ci, ci, ci, ci};
#pragma unroll
                    for (int mt = 0; mt < MT; ++mt)
#if MFMA1_K16
                        acc1[mt][ntl] = __builtin_amdgcn_mfma_f32_16x16x16f16(av1[mt], bw1[nt], cinit, 0, 0, 0);
#else
                        acc1[mt][ntl] = __builtin_amdgcn_mfma_f32_16x16x32_f16(av1[mt], bw1[nt], cinit, 0, 0, 0);
#endif
                }
                // pack pair -> ds_write_b32 (2-way bank alias = free)
#pragma unroll
                for (int mt = 0; mt < MT; ++mt)
#pragma unroll
                    for (int r = 0; r < 4; ++r) {
                        const int m = mt * 16 + quad * 4 + r;
                        const f16x2 h = relu2(pkrtz(acc1[mt][0][r], acc1[mt][1][r]));
                        *(f16x2*)&h1s[wave][m][col * 4 + pp * 2] = h;
                    }
            }
            __threadfence_block();

            // ---- layer-2: A-frags up front, mask folded into MFMA C-operand ----
            f16x8 a2f[MT][2];
#pragma unroll
            for (int mt = 0; mt < MT; ++mt)
#pragma unroll
                for (int kt = 0; kt < 2; ++kt)
                    a2f[mt][kt] = *(const f16x8*)&h1s[wave][mt * 16 + col][kt * 32 + quad * 8];

            f32x4 cm[MT];   // C-init: 0 for valid rows, NEG for masked (free add via MFMA)
#pragma unroll
            for (int mt = 0; mt < MT; ++mt)
#pragma unroll
                for (int r = 0; r < 4; ++r)
                    cm[mt][r] = (mt * 16 + quad * 4 + r < np) ? 0.0f : NEG_;

            float hmv[4];
#pragma unroll
            for (int nt = 0; nt < 4; ++nt) {     // stream acc per nt: peak 8 acc regs
                f32x4 acc[MT];
#pragma unroll
                for (int mt = 0; mt < MT; ++mt) {
                    acc[mt] = __builtin_amdgcn_mfma_f32_16x16x32_f16(a2f[mt][0], bw2[0][nt], cm[mt], 0, 0, 0);
                    acc[mt] = __builtin_amdgcn_mfma_f32_16x16x32_f16(a2f[mt][1], bw2[1][nt], acc[mt], 0, 0, 0);
                }
                // pure max tree (max3-formable)
                float hm = fmaxf(fmaxf(acc[0][0], acc[0][1]), fmaxf(acc[0][2], acc[0][3]));
                if (MT == 2) {
                    const float t1 = fmaxf(fmaxf(acc[MT - 1][0], acc[MT - 1][1]),
                                           fmaxf(acc[MT - 1][2], acc[MT - 1][3]));
                    hm = fmaxf(hm, t1);
                }
                hm = fmaxf(hm, __shfl_xor(hm, 16, 64));
                hm = fmaxf(hm, __shfl_xor(hm, 32, 64));
                hmv[nt] = hm;
            }
            float r0 = (quad == 0) ? hmv[0] : (quad == 1) ? hmv[1] : (quad == 2) ? hmv[2] : hmv[3];
            return fmaxf(r0 + c2own, 0.0f);
        };

        float res;
        if (npu > 16)     res = body(std::integral_constant<int, 2>{});
        else if (npu > 0) res = body(std::integral_constant<int, 1>{});
        else              res = NEG_;
        out[(size_t)p * 64 + lane] = res;

        if (!has_next) break;
        p = pn; pv = pvn; np = npn; cy = cyn; cx = cxn;
    }
}

extern "C" void kernel_launch(void* const* d_in, const int* in_sizes, int n_in,
                              void* d_out, int out_size, void* d_ws, size_t ws_size,
                              hipStream_t stream) {
    const float* pillars = (const float*)d_in[0];
    const int*   coords  = (const int*)d_in[1];
    const int*   npts    = (const int*)d_in[2];
    const float* W1      = (const float*)d_in[3];
    const float* b1      = (const float*)d_in[4];
    const float* g1      = (const float*)d_in[5];
    const float* beta1   = (const float*)d_in[6];
    const float* m1      = (const float*)d_in[7];
    const float* v1      = (const float*)d_in[8];
    const float* W2      = (const float*)d_in[9];
    const float* b2      = (const float*)d_in[10];
    const float* g2      = (const float*)d_in[11];
    const float* beta2   = (const float*)d_in[12];
    const float* m2      = (const float*)d_in[13];
    const float* v2      = (const float*)d_in[14];
    float* out           = (float*)d_out;

    const int P = in_sizes[2];
    // 1280 blocks = 5 blocks/CU resident at 5 waves/SIMD (launch_bounds 256,5),
    // LDS 5*20KB = 100KB/CU ✓
    const int blocks = 1280;

    hipLaunchKernelGGL(pfn_kernel, dim3(blocks), dim3(256), 0, stream,
                       pillars, coords, npts, W1, b1, g1, beta1, m1, v1,
                       W2, b2, g2, beta2, m2, v2, out, P);
}

// Round 10
// 153.629 us; speedup vs baseline: 1.2250x; 1.2250x over previous
//
#include <hip/hip_runtime.h>
#include <type_traits>

#define RES_ 0.16f
#define XMIN_ -51.2f
#define YMIN_ -51.2f
#define EPS_ 1e-5f
#define NEG_ -1000000000.0f

#define WPB 4  // waves per block

typedef _Float16 f16x8 __attribute__((ext_vector_type(8)));
typedef _Float16 f16x4 __attribute__((ext_vector_type(4)));
typedef _Float16 f16x2 __attribute__((ext_vector_type(2)));
typedef float f32x4 __attribute__((ext_vector_type(4)));

union F8u { f16x8 v; f16x2 h[4]; };
union F4u { f16x4 v; f16x2 h[2]; };

#if __has_builtin(__builtin_amdgcn_mfma_f32_16x16x16f16)
#define MFMA1_K16 1
#else
#define MFMA1_K16 0
#endif

// cvt_pkrtz returns __fp16x2 on this clang; launder to _Float16x2 (same bits)
static __device__ __forceinline__ f16x2 pkrtz(float a, float b) {
    return __builtin_bit_cast(f16x2, __builtin_amdgcn_cvt_pkrtz(a, b));
}

static __device__ __forceinline__ f16x2 relu2(f16x2 x) {
#if __has_builtin(__builtin_elementwise_max)
    const f16x2 z2 = (f16x2)(_Float16)0.f;
    return __builtin_elementwise_max(x, z2);   // v_pk_max_f16
#else
    f16x2 r;
    r[0] = x[0] > (_Float16)0.f ? x[0] : (_Float16)0.f;
    r[1] = x[1] > (_Float16)0.f ? x[1] : (_Float16)0.f;
    return r;
#endif
}

// NOTE (r9 post-mortem): this kernel's resident weights (bw1+bw2+consts) need the
// 128-unified-reg tier. launch_bounds(256,5) caused scratch spills (WRITE_SIZE
// 25->47MB, dur +46%). Keep (256,4).
__global__ __launch_bounds__(256, 4) void pfn_kernel(
    const float* __restrict__ pillars,
    const int* __restrict__ coords,
    const int* __restrict__ npts_arr,
    const float* __restrict__ W1, const float* __restrict__ b1,
    const float* __restrict__ g1, const float* __restrict__ beta1,
    const float* __restrict__ m1, const float* __restrict__ v1,
    const float* __restrict__ W2, const float* __restrict__ b2,
    const float* __restrict__ g2, const float* __restrict__ beta2,
    const float* __restrict__ m2, const float* __restrict__ v2,
    float* __restrict__ out, int P)
{
    __shared__ float pts[WPB][32][4];                        // 2 KB
    __shared__ __align__(16) _Float16 h1s[WPB][32][72];      // 18 KB

    const int tid  = threadIdx.x;
    const int wave = tid >> 6;
    const int lane = tid & 63;
    const int quad = lane >> 4;
    const int col  = lane & 15;

    // ---- W1 (BN1-scale folded) as B-frags; z-correction row; bias ----
    // feat slots: {x,y,z,r,xo,yo,z,xo,yo,0..}  (z in slot 6; zo folded via acc init)
    float c1v[4], w16v[4];
#if MFMA1_K16
    f16x4 bw1[4];   // B[k=quad*4+j][n=nt*16+col], K padded 9->16
#else
    f16x8 bw1[4];   // B[k=quad*8+j][n=nt*16+col], K padded 9->32
#endif
#pragma unroll
    for (int nt = 0; nt < 4; ++nt) {
        const int n0 = nt * 16 + col;
        const float a1 = g1[n0] * rsqrtf(v1[n0] + EPS_);
        c1v[nt]  = fmaf(a1, b1[n0] - m1[n0], beta1[n0]);
        w16v[nt] = a1 * W1[6 * 64 + n0];
#if MFMA1_K16
#pragma unroll
        for (int j = 0; j < 4; ++j) {
            const int k = quad * 4 + j;
            bw1[nt][j] = (k < 9) ? (_Float16)(a1 * W1[k * 64 + n0]) : (_Float16)0.f;
        }
#else
#pragma unroll
        for (int j = 0; j < 8; ++j) {
            const int k = quad * 8 + j;
            bw1[nt][j] = (k < 9) ? (_Float16)(a1 * W1[k * 64 + n0]) : (_Float16)0.f;
        }
#endif
    }

    // ---- W2 (BN2-scale folded, k-rows permuted to match packed-h1 layout) ----
    // physical h1 index i holds original channel g(i) = (i&3)*16 + (i>>2)
    f16x8 bw2[2][4];
#pragma unroll
    for (int nt = 0; nt < 4; ++nt) {
        const int n0 = nt * 16 + col;
        const float a2 = g2[n0] * rsqrtf(v2[n0] + EPS_);
#pragma unroll
        for (int kt = 0; kt < 2; ++kt)
#pragma unroll
            for (int j = 0; j < 8; ++j) {
                const int phys = kt * 32 + quad * 8 + j;
                const int orig = (phys & 3) * 16 + (phys >> 2);
                bw2[kt][nt][j] = (_Float16)(a2 * W2[orig * 64 + n0]);
            }
    }
    // lane's own output-channel bias (applied AFTER the row-max; max is shift-equivariant)
    const float a2o   = g2[lane] * rsqrtf(v2[lane] + EPS_);
    const float c2own = fmaf(a2o, b2[lane] - m2[lane], beta2[lane]);

    const int nwaves = gridDim.x * WPB;
    int p = __builtin_amdgcn_readfirstlane(blockIdx.x * WPB + wave);
    if (p >= P) return;

    // ---- prefetch pillar 0 ----
    float2 pv = ((const float2*)(pillars + (size_t)p * 128))[lane];
    int np = npts_arr[p];
    int cy = coords[2 * p], cx = coords[2 * p + 1];

    while (true) {
        const int pn = p + nwaves;
        const bool has_next = pn < P;
        float2 pvn; int npn = 0, cyn = 0, cxn = 0;
        if (has_next) {                       // wave-uniform; issue loads early
            pvn = ((const float2*)(pillars + (size_t)pn * 128))[lane];
            npn = npts_arr[pn];
            cyn = coords[2 * pn]; cxn = coords[2 * pn + 1];
        }

        np = np < 0 ? 0 : (np > 32 ? 32 : np);
        const int npu = __builtin_amdgcn_readfirstlane(np);
        const float xc = ((float)cx + 0.5f) * RES_ + XMIN_;
        const float yc = ((float)cy + 0.5f) * RES_ + YMIN_;

        // ---- stage 32x4 points (float2/lane) ----
        ((float2*)&pts[wave][0][0])[lane] = pv;

        // ---- z-sum from registers: odd lanes hold z of point lane>>1 in pv.x ----
        float zv = ((lane & 1) && ((lane >> 1) < np)) ? pv.x : 0.0f;
#pragma unroll
        for (int off = 1; off <= 32; off <<= 1) zv += __shfl_xor(zv, off, 64);
        const float z_mean = zv / fmaxf((float)np, 1.0f);

        __threadfence_block();   // drain pts writes (wave-lockstep)

        // ================= pillar body, specialized on row-tile count =================
        auto body = [&](auto MTC) -> float {
            constexpr int MT = decltype(MTC)::value;

            // ---- layer-1 A-frags ----
#if MFMA1_K16
            f16x4 av1[MT];   // A[m=mt*16+col][k=quad*4+j]
#else
            f16x8 av1[MT];   // A[m=mt*16+col][k=quad*8+j]
#endif
#pragma unroll
            for (int mt = 0; mt < MT; ++mt) {
                const float4 pt = *(const float4*)&pts[wave][mt * 16 + col][0];
                const float xo = pt.x - xc;
                const float yo = pt.y - yc;
                const f16x2 c01 = pkrtz(pt.x, pt.y);
                const f16x2 c23 = pkrtz(pt.z, pt.w);
                const f16x2 c45 = pkrtz(xo, yo);
                const f16x2 c67 = pkrtz(pt.z, xo);   // slot6=z (zo corrected in C), slot7=xo
                const f16x2 c89 = pkrtz(yo, 0.0f);
                const f16x2 z2  = (f16x2)(_Float16)0.f;
#if MFMA1_K16
                F4u u;
                u.h[0] = (quad == 0) ? c01 : (quad == 1) ? c45 : (quad == 2) ? c89 : z2;
                u.h[1] = (quad == 0) ? c23 : (quad == 1) ? c67 : z2;
                av1[mt] = u.v;
#else
                F8u u;
                u.h[0] = (quad == 0) ? c01 : (quad == 1) ? c89 : z2;
                u.h[1] = (quad == 0) ? c23 : z2;
                u.h[2] = (quad == 0) ? c45 : z2;
                u.h[3] = (quad == 0) ? c67 : z2;
                av1[mt] = u.v;
#endif
            }

            // ---- layer-1 MFMA with bias + z-correction in C ----
            f32x4 acc1[MT][4];
#pragma unroll
            for (int nt = 0; nt < 4; ++nt) {
                const float ci = fmaf(-z_mean, w16v[nt], c1v[nt]);
                const f32x4 cinit = {ci, ci, ci, ci};
#pragma unroll
                for (int mt = 0; mt < MT; ++mt)
#if MFMA1_K16
                    acc1[mt][nt] = __builtin_amdgcn_mfma_f32_16x16x16f16(av1[mt], bw1[nt], cinit, 0, 0, 0);
#else
                    acc1[mt][nt] = __builtin_amdgcn_mfma_f32_16x16x32_f16(av1[mt], bw1[nt], cinit, 0, 0, 0);
#endif
            }

            // ---- epi1: pack + packed relu -> one b64 LDS write per (mt,r) ----
#pragma unroll
            for (int mt = 0; mt < MT; ++mt)
#pragma unroll
                for (int r = 0; r < 4; ++r) {
                    const int m = mt * 16 + quad * 4 + r;
                    F4u w;
                    w.h[0] = relu2(pkrtz(acc1[mt][0][r], acc1[mt][1][r]));
                    w.h[1] = relu2(pkrtz(acc1[mt][2][r], acc1[mt][3][r]));
                    *(f16x4*)&h1s[wave][m][col * 4] = w.v;   // ds_write_b64
                }
            __threadfence_block();

            // ---- layer-2: A-frags, mask folded into MFMA C-operand (free adds) ----
            f16x8 a2f[MT][2];
#pragma unroll
            for (int mt = 0; mt < MT; ++mt)
#pragma unroll
                for (int kt = 0; kt < 2; ++kt)
                    a2f[mt][kt] = *(const f16x8*)&h1s[wave][mt * 16 + col][kt * 32 + quad * 8];

            f32x4 cm[MT];   // 0 for valid rows, NEG for masked
#pragma unroll
            for (int mt = 0; mt < MT; ++mt)
#pragma unroll
                for (int r = 0; r < 4; ++r)
                    cm[mt][r] = (mt * 16 + quad * 4 + r < np) ? 0.0f : NEG_;

            float hmv[4];
#pragma unroll
            for (int nt = 0; nt < 4; ++nt) {     // stream acc per nt (short live ranges)
                f32x4 acc[MT];
#pragma unroll
                for (int mt = 0; mt < MT; ++mt) {
                    acc[mt] = __builtin_amdgcn_mfma_f32_16x16x32_f16(a2f[mt][0], bw2[0][nt], cm[mt], 0, 0, 0);
                    acc[mt] = __builtin_amdgcn_mfma_f32_16x16x32_f16(a2f[mt][1], bw2[1][nt], acc[mt], 0, 0, 0);
                }
                // pure max tree (max3-formable)
                float hm = fmaxf(fmaxf(acc[0][0], acc[0][1]), fmaxf(acc[0][2], acc[0][3]));
                if (MT == 2) {
                    const float t1 = fmaxf(fmaxf(acc[MT - 1][0], acc[MT - 1][1]),
                                           fmaxf(acc[MT - 1][2], acc[MT - 1][3]));
                    hm = fmaxf(hm, t1);
                }
                hm = fmaxf(hm, __shfl_xor(hm, 16, 64));
                hm = fmaxf(hm, __shfl_xor(hm, 32, 64));
                hmv[nt] = hm;
            }
            float r0 = (quad == 0) ? hmv[0] : (quad == 1) ? hmv[1] : (quad == 2) ? hmv[2] : hmv[3];
            return fmaxf(r0 + c2own, 0.0f);
        };

        float res;
        if (npu > 16)     res = body(std::integral_constant<int, 2>{});
        else if (npu > 0) res = body(std::integral_constant<int, 1>{});
        else              res = NEG_;
        out[(size_t)p * 64 + lane] = res;

        if (!has_next) break;
        p = pn; pv = pvn; np = npn; cy = cyn; cx = cxn;
    }
}

extern "C" void kernel_launch(void* const* d_in, const int* in_sizes, int n_in,
                              void* d_out, int out_size, void* d_ws, size_t ws_size,
                              hipStream_t stream) {
    const float* pillars = (const float*)d_in[0];
    const int*   coords  = (const int*)d_in[1];
    const int*   npts    = (const int*)d_in[2];
    const float* W1      = (const float*)d_in[3];
    const float* b1      = (const float*)d_in[4];
    const float* g1      = (const float*)d_in[5];
    const float* beta1   = (const float*)d_in[6];
    const float* m1      = (const float*)d_in[7];
    const float* v1      = (const float*)d_in[8];
    const float* W2      = (const float*)d_in[9];
    const float* b2      = (const float*)d_in[10];
    const float* g2      = (const float*)d_in[11];
    const float* beta2   = (const float*)d_in[12];
    const float* m2      = (const float*)d_in[13];
    const float* v2      = (const float*)d_in[14];
    float* out           = (float*)d_out;

    const int P = in_sizes[2];
    // 1024 blocks = 4 blocks/CU resident at 4 waves/SIMD (launch_bounds 256,4)
    const int blocks = 1024;

    hipLaunchKernelGGL(pfn_kernel, dim3(blocks), dim3(256), 0, stream,
                       pillars, coords, npts, W1, b1, g1, beta1, m1, v1,
                       W2, b2, g2, beta2, m2, v2, out, P);
}

// Round 11
// 151.267 us; speedup vs baseline: 1.2442x; 1.0156x over previous
//
#include <hip/hip_runtime.h>
#include <type_traits>

#define RES_ 0.16f
#define XMIN_ -51.2f
#define YMIN_ -51.2f
#define EPS_ 1e-5f
#define NEG_ -1000000000.0f

#define WPB 4  // waves per block

typedef _Float16 f16x8 __attribute__((ext_vector_type(8)));
typedef _Float16 f16x4 __attribute__((ext_vector_type(4)));
typedef _Float16 f16x2 __attribute__((ext_vector_type(2)));
typedef float f32x4 __attribute__((ext_vector_type(4)));

union F8u { f16x8 v; f16x2 h[4]; };
union F4u { f16x4 v; f16x2 h[2]; };

// cvt_pkrtz returns __fp16x2 on this clang; launder to _Float16x2 (same bits)
static __device__ __forceinline__ f16x2 pkrtz(float a, float b) {
    return __builtin_bit_cast(f16x2, __builtin_amdgcn_cvt_pkrtz(a, b));
}

static __device__ __forceinline__ f16x2 relu2(f16x2 x) {
#if __has_builtin(__builtin_elementwise_max)
    const f16x2 z2 = (f16x2)(_Float16)0.f;
    return __builtin_elementwise_max(x, z2);   // v_pk_max_f16
#else
    f16x2 r;
    r[0] = x[0] > (_Float16)0.f ? x[0] : (_Float16)0.f;
    r[1] = x[1] > (_Float16)0.f ? x[1] : (_Float16)0.f;
    return r;
#endif
}

// NOTE (r9): resident weights need the 128-unified-reg tier; (256,5) spilled.
// NOTE (r11): zero-LDS dataflow — layer-1 computed transposed (W1^T @ feat^T) so
// its MFMA C-output IS layer-2's A-operand under a W2 k-row permutation
// c(kt,quad,j)=32kt+16(j>>2)+4quad+(j&3). No LDS staging, no h1 round-trip.
__global__ __launch_bounds__(256, 4) void pfn_kernel(
    const float* __restrict__ pillars,
    const int* __restrict__ coords,
    const int* __restrict__ npts_arr,
    const float* __restrict__ W1, const float* __restrict__ b1,
    const float* __restrict__ g1, const float* __restrict__ beta1,
    const float* __restrict__ m1, const float* __restrict__ v1,
    const float* __restrict__ W2, const float* __restrict__ b2,
    const float* __restrict__ g2, const float* __restrict__ beta2,
    const float* __restrict__ m2, const float* __restrict__ v2,
    float* __restrict__ out, int P)
{
    const int tid  = threadIdx.x;
    const int wave = tid >> 6;
    const int lane = tid & 63;
    const int quad = lane >> 4;
    const int col  = lane & 15;

    // ---- W1^T as layer-1 A-frags (K padded 9->16), BN1 scale+bias+z folded ----
    // A[m = mtile*16+col (channel)][k = quad*4+j (feat slot)]
    // slots: {x,y,z,r,xo,yo,z,xo,yo, 1.0(bias), -z_mean(w6 again), 0...}
    f16x4 aw1[4];
#pragma unroll
    for (int mt = 0; mt < 4; ++mt) {
        const int ch = mt * 16 + col;
        const float a1 = g1[ch] * rsqrtf(v1[ch] + EPS_);
        const float c1 = fmaf(a1, b1[ch] - m1[ch], beta1[ch]);
#pragma unroll
        for (int j = 0; j < 4; ++j) {
            const int k = quad * 4 + j;
            float w;
            if (k < 9)       w = a1 * W1[k * 64 + ch];
            else if (k == 9)  w = c1;                      // bias slot (feat=1.0)
            else if (k == 10) w = a1 * W1[6 * 64 + ch];    // z_mean slot (feat=-zm)
            else              w = 0.0f;
            aw1[mt][j] = (_Float16)w;
        }
    }

    // ---- W2 (BN2-scale folded), k-rows permuted to match in-register h1 layout ----
    f16x8 bw2[2][4];
#pragma unroll
    for (int nt = 0; nt < 4; ++nt) {
        const int n0 = nt * 16 + col;
        const float a2 = g2[n0] * rsqrtf(v2[n0] + EPS_);
#pragma unroll
        for (int kt = 0; kt < 2; ++kt)
#pragma unroll
            for (int j = 0; j < 8; ++j) {
                const int c = 32 * kt + 16 * (j >> 2) + 4 * quad + (j & 3);
                bw2[kt][nt][j] = (_Float16)(a2 * W2[c * 64 + n0]);
            }
    }
    // lane's own output-channel bias (applied AFTER the row-max; max is shift-equivariant)
    const float c2own = fmaf(g2[lane] * rsqrtf(v2[lane] + EPS_),
                             b2[lane] - m2[lane], beta2[lane]);

    const int nwaves = gridDim.x * WPB;
    int p = __builtin_amdgcn_readfirstlane(blockIdx.x * WPB + wave);
    if (p >= P) return;

    // ---- prefetch pillar 0: lane reads point `col` and `16+col` (quad-replicated) ----
    const float4* pb = (const float4*)(pillars + (size_t)p * 128);
    float4 ptA = pb[col];
    float4 ptB = pb[16 + col];
    int np = npts_arr[p];
    int cy = coords[2 * p], cx = coords[2 * p + 1];

    while (true) {
        const int pn = p + nwaves;
        const bool has_next = pn < P;
        float4 ptAn, ptBn; int npn = 0, cyn = 0, cxn = 0;
        if (has_next) {                       // wave-uniform; issue loads early
            const float4* pbn = (const float4*)(pillars + (size_t)pn * 128);
            ptAn = pbn[col];
            ptBn = pbn[16 + col];
            npn = npts_arr[pn];
            cyn = coords[2 * pn]; cxn = coords[2 * pn + 1];
        }

        np = np < 0 ? 0 : (np > 32 ? 32 : np);
        const int npu = __builtin_amdgcn_readfirstlane(np);
        const float xc = ((float)cx + 0.5f) * RES_ + XMIN_;
        const float yc = ((float)cy + 0.5f) * RES_ + YMIN_;

        // ---- z_mean: lane holds z of its two points; reduce over 16 cols ----
        float zs = (col < np) ? ptA.z : 0.0f;
        zs += (16 + col < np) ? ptB.z : 0.0f;
#pragma unroll
        for (int off = 1; off <= 8; off <<= 1) zs += __shfl_xor(zs, off, 64);
        const float z_mean = zs / fmaxf((float)np, 1.0f);

        // ================= pillar body (zero LDS) =================
        auto body = [&](auto MTC) -> float {
            constexpr int MT = decltype(MTC)::value;
            float hm4[4] = {NEG_, NEG_, NEG_, NEG_};

#pragma unroll
            for (int t = 0; t < MT; ++t) {
                const float4 pt = (t == 0) ? ptA : ptB;

                // ---- feat^T B-frag: B[k=quad*4+j][n=point col] ----
                const float xo = pt.x - xc;
                const float yo = pt.y - yc;
                const f16x2 c01 = pkrtz(pt.x, pt.y);       // quad0: x,y
                const f16x2 c23 = pkrtz(pt.z, pt.w);       // quad0: z,r
                const f16x2 c45 = pkrtz(xo, yo);           // quad1: xo,yo
                const f16x2 c67 = pkrtz(pt.z, xo);         // quad1: z(slot6), xo
                const f16x2 c89 = pkrtz(yo, 1.0f);         // quad2: yo, bias-1
                const f16x2 cab = pkrtz(-z_mean, 0.0f);    // quad2: -zm, 0
                const f16x2 z2  = (f16x2)(_Float16)0.f;
                F4u u;
                u.h[0] = (quad == 0) ? c01 : (quad == 1) ? c45 : (quad == 2) ? c89 : z2;
                u.h[1] = (quad == 0) ? c23 : (quad == 1) ? c67 : (quad == 2) ? cab : z2;
                const f16x4 bt = u.v;

                // ---- layer-1: 4 MFMAs, C=0 (bias+z in K-slots) ----
                f32x4 acc1[4];
                const f32x4 zz = {0.f, 0.f, 0.f, 0.f};
#pragma unroll
                for (int mt = 0; mt < 4; ++mt)
                    acc1[mt] = __builtin_amdgcn_mfma_f32_16x16x16f16(aw1[mt], bt, zz, 0, 0, 0);

                // ---- h1 relu + pack: layer-2 A-frags, pure in-lane ----
                f16x8 av2[2];
#pragma unroll
                for (int kt = 0; kt < 2; ++kt) {
                    F8u w;
                    w.h[0] = relu2(pkrtz(acc1[2 * kt][0],     acc1[2 * kt][1]));
                    w.h[1] = relu2(pkrtz(acc1[2 * kt][2],     acc1[2 * kt][3]));
                    w.h[2] = relu2(pkrtz(acc1[2 * kt + 1][0], acc1[2 * kt + 1][1]));
                    w.h[3] = relu2(pkrtz(acc1[2 * kt + 1][2], acc1[2 * kt + 1][3]));
                    av2[kt] = w.v;
                }

                // ---- row-mask as layer-2 C-init (free adds) ----
                f32x4 cm;
#pragma unroll
                for (int r = 0; r < 4; ++r)
                    cm[r] = (t * 16 + quad * 4 + r < np) ? 0.0f : NEG_;

                // ---- layer-2: stream per nt, fold into running max ----
#pragma unroll
                for (int nt = 0; nt < 4; ++nt) {
                    f32x4 acc = __builtin_amdgcn_mfma_f32_16x16x32_f16(av2[0], bw2[0][nt], cm, 0, 0, 0);
                    acc = __builtin_amdgcn_mfma_f32_16x16x32_f16(av2[1], bw2[1][nt], acc, 0, 0, 0);
                    const float tmax = fmaxf(fmaxf(acc[0], acc[1]), fmaxf(acc[2], acc[3]));
                    hm4[nt] = fmaxf(hm4[nt], tmax);
                }
            }

            // ---- cross-quad max, select own channel, bias+relu ----
            float hmv[4];
#pragma unroll
            for (int nt = 0; nt < 4; ++nt) {
                float hm = hm4[nt];
                hm = fmaxf(hm, __shfl_xor(hm, 16, 64));
                hm = fmaxf(hm, __shfl_xor(hm, 32, 64));
                hmv[nt] = hm;
            }
            float r0 = (quad == 0) ? hmv[0] : (quad == 1) ? hmv[1] : (quad == 2) ? hmv[2] : hmv[3];
            return fmaxf(r0 + c2own, 0.0f);
        };

        float res;
        if (npu > 16)     res = body(std::integral_constant<int, 2>{});
        else if (npu > 0) res = body(std::integral_constant<int, 1>{});
        else              res = NEG_;
        out[(size_t)p * 64 + lane] = res;

        if (!has_next) break;
        p = pn; ptA = ptAn; ptB = ptBn; np = npn; cy = cyn; cx = cxn;
    }
}

extern "C" void kernel_launch(void* const* d_in, const int* in_sizes, int n_in,
                              void* d_out, int out_size, void* d_ws, size_t ws_size,
                              hipStream_t stream) {
    const float* pillars = (const float*)d_in[0];
    const int*   coords  = (const int*)d_in[1];
    const int*   npts    = (const int*)d_in[2];
    const float* W1      = (const float*)d_in[3];
    const float* b1      = (const float*)d_in[4];
    const float* g1      = (const float*)d_in[5];
    const float* beta1   = (const float*)d_in[6];
    const float* m1      = (const float*)d_in[7];
    const float* v1      = (const float*)d_in[8];
    const float* W2      = (const float*)d_in[9];
    const float* b2      = (const float*)d_in[10];
    const float* g2      = (const float*)d_in[11];
    const float* beta2   = (const float*)d_in[12];
    const float* m2      = (const float*)d_in[13];
    const float* v2      = (const float*)d_in[14];
    float* out           = (float*)d_out;

    const int P = in_sizes[2];
    // 1024 blocks = 4 blocks/CU resident at 4 waves/SIMD (launch_bounds 256,4)
    const int blocks = 1024;

    hipLaunchKernelGGL(pfn_kernel, dim3(blocks), dim3(256), 0, stream,
                       pillars, coords, npts, W1, b1, g1, beta1, m1, v1,
                       W2, b2, g2, beta2, m2, v2, out, P);
}